// Round 11
// baseline (188.434 us; speedup 1.0000x reference)
//
#include <hip/hip_runtime.h>
#include <stdint.h>

#define BB 64
#define PP 24656
#define CC 81
#define NEGPOS 3
#define RPT 16                     // rows per wave tile
#define TB (RPT * CC * 4)          // 5184 B = 324 float4
#define TFLT (RPT * CC)            // 1296 floats
#define NT ((BB * PP) / RPT)       // 98624 tiles
#define ROWS (BB * PP)
#define NBLK 1792                  // 7 blocks/CU -> 28 waves/CU

typedef unsigned int u32;
typedef unsigned long long u64;

// ws layout:
//   [0]      int num_pos[64]
//   [256]    double blk[64][4]   (l, o, cp, sel) per batch row
//   [4096]   float mine[ROWS]

// ---------------- k_main: R10 structure, but staging = plain float4 loads ->
// registers -> ds_write (tests/beats the global_load_lds DMA-queue limit).
// Compute phase consumes ZERO VMEM results. ----------------
__global__ __launch_bounds__(256, 7) void k_main(
    const float* __restrict__ conf_data,
    const int*   __restrict__ conf_t,
    float* __restrict__ mine)
{
    __shared__ __align__(16) float tile[4][TFLT];   // 20736 B -> 7 blocks/CU
    const int t = threadIdx.x;
    const int w = t >> 6;
    const int lane = t & 63;
    const int r = lane >> 2;        // row within tile
    const int s = lane & 3;         // quarter-row segment
    float4* wt4 = (float4*)tile[w];
    const float* wt = tile[w];
    const int wid = blockIdx.x * 4 + w;
    const int nw = NBLK * 4;        // 7168 waves

    float4 b0, b1, b2, b3, b4, bt;
    int tc_nxt = 0;

    // prologue: issue loads for tile(wid)
    {
        const float4* gb = (const float4*)(conf_data + (long)wid * TFLT);
        b0 = gb[lane];
        b1 = gb[64 + lane];
        b2 = gb[128 + lane];
        b3 = gb[192 + lane];
        b4 = gb[256 + lane];
        if (lane < 4) bt = gb[320 + lane];
        if (lane < 16) tc_nxt = conf_t[(long)wid * RPT + lane];
    }

    for (int td = wid; td < NT; td += nw) {
        // ---- stage regs -> LDS (compiler inserts counted vmcnt wait) ----
        wt4[lane]       = b0;
        wt4[64 + lane]  = b1;
        wt4[128 + lane] = b2;
        wt4[192 + lane] = b3;
        wt4[256 + lane] = b4;
        if (lane < 4) wt4[320 + lane] = bt;
        const int tc_cur = tc_nxt;

        // ---- issue next tile's loads (in flight across compute) ----
        const int tdn = td + nw;
        if (tdn < NT) {
            const float4* gb = (const float4*)(conf_data + (long)tdn * TFLT);
            b0 = gb[lane];
            b1 = gb[64 + lane];
            b2 = gb[128 + lane];
            b3 = gb[192 + lane];
            b4 = gb[256 + lane];
            if (lane < 4) bt = gb[320 + lane];
            if (lane < 16) tc_nxt = conf_t[(long)tdn * RPT + lane];
        }

        // ---- compute from LDS (DS in-order per wave; no VMEM consumed) ----
        const float* rp = wt + r * CC;
        const int start = (s == 0) ? 0 : (s * 20 + 1);     // 21|20|20|20 split
        float sum = (s == 0) ? __expf(rp[20]) : 0.0f;
        #pragma unroll
        for (int j = 0; j < 20; ++j) sum += __expf(rp[start + j]);
        sum += __shfl_xor(sum, 1, 64);
        sum += __shfl_xor(sum, 2, 64);     // 4 lanes of a row hold the row sum

        const int tc_v = __shfl(tc_cur, r, 64);   // row r's target class
        if (s == 0) {
            const float cat = rp[tc_v];
            mine[(long)td * RPT + r] = fmaxf(__logf(sum) - cat, 0.0f);
        }
    }
}

// ---------------- k_select: per batch row — pos mask, np, a_cp/a_l/a_o,
// then radix k-th largest via ballot-match histogram. ----------------
__global__ __launch_bounds__(1024) void k_select(
    const float* __restrict__ mine,
    const int*   __restrict__ conf_t,
    const float* __restrict__ loc_data,
    const float* __restrict__ loc_t,
    const float* __restrict__ occ_data,
    const float* __restrict__ occ_t,
    double* __restrict__ blk,     // [BB][4]
    int* __restrict__ num_pos)    // [BB]
{
    __shared__ u32 hist[256];
    __shared__ u32 sh_prefix, sh_kk;
    __shared__ double dred[16][3];
    __shared__ int ired[16];
    __shared__ double dsum[16];
    __shared__ u32 cred[16];

    const int b = blockIdx.x;
    const int t = threadIdx.x;
    const int w = t >> 6;
    const int lane = t & 63;
    const long base = (long)b * PP;
    const float* row = mine + base;
    const int* tcr = conf_t + base;

    u32 u[25];
    int np_t = 0;
    double a_l = 0.0, a_o = 0.0, a_cp = 0.0;

    #pragma unroll
    for (int r2 = 0; r2 < 25; ++r2) {
        const int idx = t + (r2 << 10);
        u32 uu = 0u;
        if (idx < PP) {
            uu = __float_as_uint(row[idx]);
            const int tc = tcr[idx];
            if (tc > 0) {
                ++np_t;
                a_cp += (double)__uint_as_float(uu);
                const long i = base + idx;
                const float4 ld4 = *(const float4*)(loc_data + i * 4);
                const float4 lt4 = *(const float4*)(loc_t + i * 4);
                float sl = 0.0f;
                { float d = ld4.x - lt4.x, ad = fabsf(d); sl += (ad < 1.f) ? 0.5f*d*d : ad - 0.5f; }
                { float d = ld4.y - lt4.y, ad = fabsf(d); sl += (ad < 1.f) ? 0.5f*d*d : ad - 0.5f; }
                { float d = ld4.z - lt4.z, ad = fabsf(d); sl += (ad < 1.f) ? 0.5f*d*d : ad - 0.5f; }
                { float d = ld4.w - lt4.w, ad = fabsf(d); sl += (ad < 1.f) ? 0.5f*d*d : ad - 0.5f; }
                a_l += (double)sl;
                const float ot = occ_t[i];
                if (ot != -1.0f) { const float dd = occ_data[i] - ot; a_o += (double)(dd * dd); }
                uu = 0u;                       // exclude pos from mining
            }
        }
        u[r2] = uu;
    }

    #pragma unroll
    for (int d = 1; d < 64; d <<= 1) {
        a_l  += __shfl_xor(a_l,  d, 64);
        a_o  += __shfl_xor(a_o,  d, 64);
        a_cp += __shfl_xor(a_cp, d, 64);
        np_t += __shfl_xor(np_t, d, 64);
    }
    if (lane == 0) { dred[w][0] = a_l; dred[w][1] = a_o; dred[w][2] = a_cp; ired[w] = np_t; }
    __syncthreads();
    int np = 0;
    #pragma unroll
    for (int j = 0; j < 16; ++j) np += ired[j];
    if (t == 0) {
        double L = 0, O = 0, Cp = 0;
        #pragma unroll
        for (int j = 0; j < 16; ++j) { L += dred[j][0]; O += dred[j][1]; Cp += dred[j][2]; }
        blk[b * 4 + 0] = L;
        blk[b * 4 + 1] = O;
        blk[b * 4 + 2] = Cp;
        num_pos[b] = np;
    }

    int k = NEGPOS * np;
    if (k > PP - 1) k = PP - 1;
    if (k <= 0) {                    // uniform across block
        if (t == 0) blk[b * 4 + 3] = 0.0;
        return;
    }

    u32 prefix = 0, mask = 0, kk = (u32)k;

    for (int pass = 0; pass < 4; ++pass) {
        const int shift = 24 - 8 * pass;
        if (t < 256) hist[t] = 0;
        __syncthreads();
        #pragma unroll
        for (int r2 = 0; r2 < 25; ++r2) {
            const u32 uu = u[r2];
            const bool valid = (uu & mask) == prefix;
            const u32 bin = (uu >> shift) & 255u;
            u64 eq = __ballot(valid);
            #pragma unroll
            for (int bi = 0; bi < 8; ++bi) {
                const u64 bal = __ballot((bin >> bi) & 1u);
                eq &= ((bin >> bi) & 1u) ? bal : ~bal;
            }
            if (valid && ((int)__ffsll(eq) - 1 == lane))
                atomicAdd(&hist[bin], (u32)__popcll(eq));
        }
        __syncthreads();
        if (t < 256) {
            u32 above = 0;
            for (int bb = t + 1; bb < 256; ++bb) above += hist[bb];
            if (above < kk && above + hist[t] >= kk) {   // exactly one bin
                sh_prefix = prefix | ((u32)t << shift);
                sh_kk = kk - above;
            }
        }
        __syncthreads();
        prefix = sh_prefix;
        kk = sh_kk;
        mask |= (0xFFu << shift);
        __syncthreads();
    }

    const u32 thr_bits = prefix;
    const float thr = __uint_as_float(thr_bits);

    double ssum = 0.0;
    u32 cnt = 0;
    #pragma unroll
    for (int r2 = 0; r2 < 25; ++r2) {
        const u32 uu = u[r2];
        if (uu > thr_bits) { ssum += (double)__uint_as_float(uu); cnt++; }
    }
    #pragma unroll
    for (int d = 1; d < 64; d <<= 1) {
        ssum += __shfl_xor(ssum, d, 64);
        cnt  += __shfl_xor(cnt,  d, 64);
    }
    if (lane == 0) { dsum[w] = ssum; cred[w] = cnt; }
    __syncthreads();
    if (t == 0) {
        double S = 0.0; u32 cg = 0;
        #pragma unroll
        for (int j = 0; j < 16; ++j) { S += dsum[j]; cg += cred[j]; }
        S += (double)(k - (int)cg) * (double)thr;   // ties at threshold value
        blk[b * 4 + 3] = S;
    }
}

// ---------------- k_final ----------------
__global__ __launch_bounds__(64) void k_final(
    const double* __restrict__ blk,
    const int* __restrict__ num_pos,
    float* __restrict__ out)
{
    const int t = threadIdx.x;   // t == batch row
    double l  = blk[t * 4 + 0];
    double o  = blk[t * 4 + 1];
    double cp = blk[t * 4 + 2];
    double se = blk[t * 4 + 3];
    double n  = (double)num_pos[t];
    #pragma unroll
    for (int d = 1; d < 64; d <<= 1) {
        l  += __shfl_xor(l,  d, 64);
        o  += __shfl_xor(o,  d, 64);
        cp += __shfl_xor(cp, d, 64);
        se += __shfl_xor(se, d, 64);
        n  += __shfl_xor(n,  d, 64);
    }
    if (t == 0) {
        out[0] = (float)(l / n);
        out[1] = (float)((cp + se) / n);
        out[2] = (float)(o / n);
    }
}

extern "C" void kernel_launch(void* const* d_in, const int* in_sizes, int n_in,
                              void* d_out, int out_size, void* d_ws, size_t ws_size,
                              hipStream_t stream) {
    const float* loc_data  = (const float*)d_in[0];
    const float* conf_data = (const float*)d_in[1];
    const float* occ_data  = (const float*)d_in[2];
    const float* loc_t     = (const float*)d_in[3];
    const int*   conf_t    = (const int*)d_in[4];
    const float* occ_t     = (const float*)d_in[5];

    char* ws = (char*)d_ws;
    int*    numpos = (int*)ws;               // 64 ints
    double* blk    = (double*)(ws + 256);    // 64*4 doubles
    float*  mine   = (float*)(ws + 4096);    // ROWS floats

    k_main<<<NBLK, 256, 0, stream>>>(conf_data, conf_t, mine);
    k_select<<<BB, 1024, 0, stream>>>(mine, conf_t, loc_data, loc_t,
                                      occ_data, occ_t, blk, numpos);
    k_final<<<1, 64, 0, stream>>>(blk, numpos, (float*)d_out);
}

// Round 13
// 169.398 us; speedup vs baseline: 1.1124x; 1.1124x over previous
//
#include <hip/hip_runtime.h>
#include <stdint.h>

#define BB 64
#define PP 24656
#define CC 81
#define NEGPOS 3
#define RPT 16                     // rows per wave tile
#define TB (RPT * CC * 4)          // 5184 B = 324 float4
#define TFLT (RPT * CC)            // 1296 floats
#define NT ((BB * PP) / RPT)       // 98624 tiles
#define ROWS (BB * PP)
#define NBLK 1792                  // 7 blocks/CU -> 28 waves/CU

typedef unsigned int u32;
typedef unsigned long long u64;
typedef float f4v __attribute__((ext_vector_type(4)));

// ws layout:
//   [0]      int num_pos[64]
//   [256]    double blk[64][4]   (l, o, cp, sel) per batch row
//   [4096]   float mine[ROWS]

// ---------------- k_main: R11 structure, conf_data/conf_t via NON-TEMPORAL
// loads (no L2/L3 allocate). Tests the cache-fill-allocation hypothesis. ----
__global__ __launch_bounds__(256, 7) void k_main(
    const float* __restrict__ conf_data,
    const int*   __restrict__ conf_t,
    float* __restrict__ mine)
{
    __shared__ __align__(16) float tile[4][TFLT];   // 20736 B -> 7 blocks/CU
    const int t = threadIdx.x;
    const int w = t >> 6;
    const int lane = t & 63;
    const int r = lane >> 2;        // row within tile
    const int s = lane & 3;         // quarter-row segment
    f4v* wt4 = (f4v*)tile[w];
    const float* wt = tile[w];
    const int wid = blockIdx.x * 4 + w;
    const int nw = NBLK * 4;        // 7168 waves

    f4v b0, b1, b2, b3, b4, bt;
    int tc_nxt = 0;

    // prologue: issue NT loads for tile(wid)
    {
        const f4v* gb = (const f4v*)(conf_data + (long)wid * TFLT);
        b0 = __builtin_nontemporal_load(&gb[lane]);
        b1 = __builtin_nontemporal_load(&gb[64 + lane]);
        b2 = __builtin_nontemporal_load(&gb[128 + lane]);
        b3 = __builtin_nontemporal_load(&gb[192 + lane]);
        b4 = __builtin_nontemporal_load(&gb[256 + lane]);
        bt = b0;
        if (lane < 4)  bt = __builtin_nontemporal_load(&gb[320 + lane]);
        if (lane < 16) tc_nxt = __builtin_nontemporal_load(&conf_t[(long)wid * RPT + lane]);
    }

    for (int td = wid; td < NT; td += nw) {
        // ---- stage regs -> LDS (compiler inserts counted vmcnt wait) ----
        wt4[lane]       = b0;
        wt4[64 + lane]  = b1;
        wt4[128 + lane] = b2;
        wt4[192 + lane] = b3;
        wt4[256 + lane] = b4;
        if (lane < 4) wt4[320 + lane] = bt;
        const int tc_cur = tc_nxt;

        // ---- issue next tile's NT loads (in flight across compute) ----
        const int tdn = td + nw;
        if (tdn < NT) {
            const f4v* gb = (const f4v*)(conf_data + (long)tdn * TFLT);
            b0 = __builtin_nontemporal_load(&gb[lane]);
            b1 = __builtin_nontemporal_load(&gb[64 + lane]);
            b2 = __builtin_nontemporal_load(&gb[128 + lane]);
            b3 = __builtin_nontemporal_load(&gb[192 + lane]);
            b4 = __builtin_nontemporal_load(&gb[256 + lane]);
            if (lane < 4)  bt = __builtin_nontemporal_load(&gb[320 + lane]);
            if (lane < 16) tc_nxt = __builtin_nontemporal_load(&conf_t[(long)tdn * RPT + lane]);
        }

        // ---- compute from LDS (DS in-order per wave; no VMEM consumed) ----
        const float* rp = wt + r * CC;
        const int start = (s == 0) ? 0 : (s * 20 + 1);     // 21|20|20|20 split
        float sum = (s == 0) ? __expf(rp[20]) : 0.0f;
        #pragma unroll
        for (int j = 0; j < 20; ++j) sum += __expf(rp[start + j]);
        sum += __shfl_xor(sum, 1, 64);
        sum += __shfl_xor(sum, 2, 64);     // 4 lanes of a row hold the row sum

        const int tc_v = __shfl(tc_cur, r, 64);   // row r's target class
        if (s == 0) {
            const float cat = rp[tc_v];
            mine[(long)td * RPT + r] = fmaxf(__logf(sum) - cat, 0.0f);
        }
    }
}

// ---------------- k_select: per batch row — pos mask, np, a_cp/a_l/a_o,
// then radix k-th largest via ballot-match histogram. ----------------
__global__ __launch_bounds__(1024) void k_select(
    const float* __restrict__ mine,
    const int*   __restrict__ conf_t,
    const float* __restrict__ loc_data,
    const float* __restrict__ loc_t,
    const float* __restrict__ occ_data,
    const float* __restrict__ occ_t,
    double* __restrict__ blk,     // [BB][4]
    int* __restrict__ num_pos)    // [BB]
{
    __shared__ u32 hist[256];
    __shared__ u32 sh_prefix, sh_kk;
    __shared__ double dred[16][3];
    __shared__ int ired[16];
    __shared__ double dsum[16];
    __shared__ u32 cred[16];

    const int b = blockIdx.x;
    const int t = threadIdx.x;
    const int w = t >> 6;
    const int lane = t & 63;
    const long base = (long)b * PP;
    const float* row = mine + base;
    const int* tcr = conf_t + base;

    u32 u[25];
    int np_t = 0;
    double a_l = 0.0, a_o = 0.0, a_cp = 0.0;

    #pragma unroll
    for (int r2 = 0; r2 < 25; ++r2) {
        const int idx = t + (r2 << 10);
        u32 uu = 0u;
        if (idx < PP) {
            uu = __float_as_uint(row[idx]);
            const int tc = tcr[idx];
            if (tc > 0) {
                ++np_t;
                a_cp += (double)__uint_as_float(uu);
                const long i = base + idx;
                const float4 ld4 = *(const float4*)(loc_data + i * 4);
                const float4 lt4 = *(const float4*)(loc_t + i * 4);
                float sl = 0.0f;
                { float d = ld4.x - lt4.x, ad = fabsf(d); sl += (ad < 1.f) ? 0.5f*d*d : ad - 0.5f; }
                { float d = ld4.y - lt4.y, ad = fabsf(d); sl += (ad < 1.f) ? 0.5f*d*d : ad - 0.5f; }
                { float d = ld4.z - lt4.z, ad = fabsf(d); sl += (ad < 1.f) ? 0.5f*d*d : ad - 0.5f; }
                { float d = ld4.w - lt4.w, ad = fabsf(d); sl += (ad < 1.f) ? 0.5f*d*d : ad - 0.5f; }
                a_l += (double)sl;
                const float ot = occ_t[i];
                if (ot != -1.0f) { const float dd = occ_data[i] - ot; a_o += (double)(dd * dd); }
                uu = 0u;                       // exclude pos from mining
            }
        }
        u[r2] = uu;
    }

    #pragma unroll
    for (int d = 1; d < 64; d <<= 1) {
        a_l  += __shfl_xor(a_l,  d, 64);
        a_o  += __shfl_xor(a_o,  d, 64);
        a_cp += __shfl_xor(a_cp, d, 64);
        np_t += __shfl_xor(np_t, d, 64);
    }
    if (lane == 0) { dred[w][0] = a_l; dred[w][1] = a_o; dred[w][2] = a_cp; ired[w] = np_t; }
    __syncthreads();
    int np = 0;
    #pragma unroll
    for (int j = 0; j < 16; ++j) np += ired[j];
    if (t == 0) {
        double L = 0, O = 0, Cp = 0;
        #pragma unroll
        for (int j = 0; j < 16; ++j) { L += dred[j][0]; O += dred[j][1]; Cp += dred[j][2]; }
        blk[b * 4 + 0] = L;
        blk[b * 4 + 1] = O;
        blk[b * 4 + 2] = Cp;
        num_pos[b] = np;
    }

    int k = NEGPOS * np;
    if (k > PP - 1) k = PP - 1;
    if (k <= 0) {                    // uniform across block
        if (t == 0) blk[b * 4 + 3] = 0.0;
        return;
    }

    u32 prefix = 0, mask = 0, kk = (u32)k;

    for (int pass = 0; pass < 4; ++pass) {
        const int shift = 24 - 8 * pass;
        if (t < 256) hist[t] = 0;
        __syncthreads();
        #pragma unroll
        for (int r2 = 0; r2 < 25; ++r2) {
            const u32 uu = u[r2];
            const bool valid = (uu & mask) == prefix;
            const u32 bin = (uu >> shift) & 255u;
            u64 eq = __ballot(valid);
            #pragma unroll
            for (int bi = 0; bi < 8; ++bi) {
                const u64 bal = __ballot((bin >> bi) & 1u);
                eq &= ((bin >> bi) & 1u) ? bal : ~bal;
            }
            if (valid && ((int)__ffsll(eq) - 1 == lane))
                atomicAdd(&hist[bin], (u32)__popcll(eq));
        }
        __syncthreads();
        if (t < 256) {
            u32 above = 0;
            for (int bb = t + 1; bb < 256; ++bb) above += hist[bb];
            if (above < kk && above + hist[t] >= kk) {   // exactly one bin
                sh_prefix = prefix | ((u32)t << shift);
                sh_kk = kk - above;
            }
        }
        __syncthreads();
        prefix = sh_prefix;
        kk = sh_kk;
        mask |= (0xFFu << shift);
        __syncthreads();
    }

    const u32 thr_bits = prefix;
    const float thr = __uint_as_float(thr_bits);

    double ssum = 0.0;
    u32 cnt = 0;
    #pragma unroll
    for (int r2 = 0; r2 < 25; ++r2) {
        const u32 uu = u[r2];
        if (uu > thr_bits) { ssum += (double)__uint_as_float(uu); cnt++; }
    }
    #pragma unroll
    for (int d = 1; d < 64; d <<= 1) {
        ssum += __shfl_xor(ssum, d, 64);
        cnt  += __shfl_xor(cnt,  d, 64);
    }
    if (lane == 0) { dsum[w] = ssum; cred[w] = cnt; }
    __syncthreads();
    if (t == 0) {
        double S = 0.0; u32 cg = 0;
        #pragma unroll
        for (int j = 0; j < 16; ++j) { S += dsum[j]; cg += cred[j]; }
        S += (double)(k - (int)cg) * (double)thr;   // ties at threshold value
        blk[b * 4 + 3] = S;
    }
}

// ---------------- k_final ----------------
__global__ __launch_bounds__(64) void k_final(
    const double* __restrict__ blk,
    const int* __restrict__ num_pos,
    float* __restrict__ out)
{
    const int t = threadIdx.x;   // t == batch row
    double l  = blk[t * 4 + 0];
    double o  = blk[t * 4 + 1];
    double cp = blk[t * 4 + 2];
    double se = blk[t * 4 + 3];
    double n  = (double)num_pos[t];
    #pragma unroll
    for (int d = 1; d < 64; d <<= 1) {
        l  += __shfl_xor(l,  d, 64);
        o  += __shfl_xor(o,  d, 64);
        cp += __shfl_xor(cp, d, 64);
        se += __shfl_xor(se, d, 64);
        n  += __shfl_xor(n,  d, 64);
    }
    if (t == 0) {
        out[0] = (float)(l / n);
        out[1] = (float)((cp + se) / n);
        out[2] = (float)(o / n);
    }
}

extern "C" void kernel_launch(void* const* d_in, const int* in_sizes, int n_in,
                              void* d_out, int out_size, void* d_ws, size_t ws_size,
                              hipStream_t stream) {
    const float* loc_data  = (const float*)d_in[0];
    const float* conf_data = (const float*)d_in[1];
    const float* occ_data  = (const float*)d_in[2];
    const float* loc_t     = (const float*)d_in[3];
    const int*   conf_t    = (const int*)d_in[4];
    const float* occ_t     = (const float*)d_in[5];

    char* ws = (char*)d_ws;
    int*    numpos = (int*)ws;               // 64 ints
    double* blk    = (double*)(ws + 256);    // 64*4 doubles
    float*  mine   = (float*)(ws + 4096);    // ROWS floats

    k_main<<<NBLK, 256, 0, stream>>>(conf_data, conf_t, mine);
    k_select<<<BB, 1024, 0, stream>>>(mine, conf_t, loc_data, loc_t,
                                      occ_data, occ_t, blk, numpos);
    k_final<<<1, 64, 0, stream>>>(blk, numpos, (float*)d_out);
}

// Round 14
// 164.702 us; speedup vs baseline: 1.1441x; 1.0285x over previous
//
#include <hip/hip_runtime.h>
#include <stdint.h>

#define BB 64
#define PP 24656
#define CC 81
#define NEGPOS 3
#define RPT 16                     // rows per wave tile
#define TFLT (RPT * CC)            // 1296 floats
#define NT ((BB * PP) / RPT)       // 98624 tiles
#define ROWS (BB * PP)
#define NBLK 1792                  // 7 blocks/CU -> 28 waves/CU

typedef unsigned int u32;
typedef unsigned long long u64;
typedef float f4v __attribute__((ext_vector_type(4)));

// ws layout:
//   [0]      int num_pos[64]
//   [256]    double blk[64][4]   (l, o, cp, sel) per batch row
//   [4096]   float mine[ROWS]    (sign bit = pos flag, magnitude = diff)

// ---------------- k_main: NT-load stream; pos flag folded into sign bit ----
__global__ __launch_bounds__(256, 7) void k_main(
    const float* __restrict__ conf_data,
    const int*   __restrict__ conf_t,
    float* __restrict__ mine)
{
    __shared__ __align__(16) float tile[4][TFLT];   // 20736 B -> 7 blocks/CU
    const int t = threadIdx.x;
    const int w = t >> 6;
    const int lane = t & 63;
    const int r = lane >> 2;        // row within tile
    const int s = lane & 3;         // quarter-row segment
    f4v* wt4 = (f4v*)tile[w];
    const float* wt = tile[w];
    const int wid = blockIdx.x * 4 + w;
    const int nw = NBLK * 4;        // 7168 waves

    f4v b0, b1, b2, b3, b4, bt;
    int tc_nxt = 0;

    // prologue: issue NT loads for tile(wid)
    {
        const f4v* gb = (const f4v*)(conf_data + (long)wid * TFLT);
        b0 = __builtin_nontemporal_load(&gb[lane]);
        b1 = __builtin_nontemporal_load(&gb[64 + lane]);
        b2 = __builtin_nontemporal_load(&gb[128 + lane]);
        b3 = __builtin_nontemporal_load(&gb[192 + lane]);
        b4 = __builtin_nontemporal_load(&gb[256 + lane]);
        bt = b0;
        if (lane < 4)  bt = __builtin_nontemporal_load(&gb[320 + lane]);
        if (lane < 16) tc_nxt = __builtin_nontemporal_load(&conf_t[(long)wid * RPT + lane]);
    }

    for (int td = wid; td < NT; td += nw) {
        // ---- stage regs -> LDS (compiler inserts counted vmcnt wait) ----
        wt4[lane]       = b0;
        wt4[64 + lane]  = b1;
        wt4[128 + lane] = b2;
        wt4[192 + lane] = b3;
        wt4[256 + lane] = b4;
        if (lane < 4) wt4[320 + lane] = bt;
        const int tc_cur = tc_nxt;

        // ---- issue next tile's NT loads (in flight across compute) ----
        const int tdn = td + nw;
        if (tdn < NT) {
            const f4v* gb = (const f4v*)(conf_data + (long)tdn * TFLT);
            b0 = __builtin_nontemporal_load(&gb[lane]);
            b1 = __builtin_nontemporal_load(&gb[64 + lane]);
            b2 = __builtin_nontemporal_load(&gb[128 + lane]);
            b3 = __builtin_nontemporal_load(&gb[192 + lane]);
            b4 = __builtin_nontemporal_load(&gb[256 + lane]);
            if (lane < 4)  bt = __builtin_nontemporal_load(&gb[320 + lane]);
            if (lane < 16) tc_nxt = __builtin_nontemporal_load(&conf_t[(long)tdn * RPT + lane]);
        }

        // ---- compute from LDS (DS in-order per wave; no VMEM consumed) ----
        const float* rp = wt + r * CC;
        const int start = (s == 0) ? 0 : (s * 20 + 1);     // 21|20|20|20 split
        float sum = (s == 0) ? __expf(rp[20]) : 0.0f;
        #pragma unroll
        for (int j = 0; j < 20; ++j) sum += __expf(rp[start + j]);
        sum += __shfl_xor(sum, 1, 64);
        sum += __shfl_xor(sum, 2, 64);     // 4 lanes of a row hold the row sum

        const int tc_v = __shfl(tc_cur, r, 64);   // row r's target class
        if (s == 0) {
            const float cat = rp[tc_v];
            const float diff = fmaxf(__logf(sum) - cat, 0.0f);
            // sign bit carries the pos flag (-0.0 included)
            mine[(long)td * RPT + r] = (tc_v > 0) ? -diff : diff;
        }
    }
}

// ---------------- k_select: per batch row — pos from sign bit, np, losses,
// then radix k-th largest via ballot-match histogram. ----------------
__global__ __launch_bounds__(1024) void k_select(
    const float* __restrict__ mine,
    const float* __restrict__ loc_data,
    const float* __restrict__ loc_t,
    const float* __restrict__ occ_data,
    const float* __restrict__ occ_t,
    double* __restrict__ blk,     // [BB][4]
    int* __restrict__ num_pos)    // [BB]
{
    __shared__ u32 hist[256];
    __shared__ u32 sh_prefix, sh_kk;
    __shared__ double dred[16][3];
    __shared__ int ired[16];
    __shared__ double dsum[16];
    __shared__ u32 cred[16];

    const int b = blockIdx.x;
    const int t = threadIdx.x;
    const int w = t >> 6;
    const int lane = t & 63;
    const long base = (long)b * PP;
    const float* row = mine + base;

    u32 u[25];
    int np_t = 0;
    double a_l = 0.0, a_o = 0.0, a_cp = 0.0;

    #pragma unroll
    for (int r2 = 0; r2 < 25; ++r2) {
        const int idx = t + (r2 << 10);
        u32 uu = 0u;
        if (idx < PP) {
            uu = __float_as_uint(row[idx]);
            if (uu >> 31) {                       // pos row (sign bit)
                ++np_t;
                a_cp += (double)__uint_as_float(uu & 0x7FFFFFFFu);
                const long i = base + idx;
                const float4 ld4 = *(const float4*)(loc_data + i * 4);
                const float4 lt4 = *(const float4*)(loc_t + i * 4);
                float sl = 0.0f;
                { float d = ld4.x - lt4.x, ad = fabsf(d); sl += (ad < 1.f) ? 0.5f*d*d : ad - 0.5f; }
                { float d = ld4.y - lt4.y, ad = fabsf(d); sl += (ad < 1.f) ? 0.5f*d*d : ad - 0.5f; }
                { float d = ld4.z - lt4.z, ad = fabsf(d); sl += (ad < 1.f) ? 0.5f*d*d : ad - 0.5f; }
                { float d = ld4.w - lt4.w, ad = fabsf(d); sl += (ad < 1.f) ? 0.5f*d*d : ad - 0.5f; }
                a_l += (double)sl;
                const float ot = occ_t[i];
                if (ot != -1.0f) { const float dd = occ_data[i] - ot; a_o += (double)(dd * dd); }
                uu = 0u;                          // exclude pos from mining
            }
        }
        u[r2] = uu;
    }

    #pragma unroll
    for (int d = 1; d < 64; d <<= 1) {
        a_l  += __shfl_xor(a_l,  d, 64);
        a_o  += __shfl_xor(a_o,  d, 64);
        a_cp += __shfl_xor(a_cp, d, 64);
        np_t += __shfl_xor(np_t, d, 64);
    }
    if (lane == 0) { dred[w][0] = a_l; dred[w][1] = a_o; dred[w][2] = a_cp; ired[w] = np_t; }
    __syncthreads();
    int np = 0;
    #pragma unroll
    for (int j = 0; j < 16; ++j) np += ired[j];
    if (t == 0) {
        double L = 0, O = 0, Cp = 0;
        #pragma unroll
        for (int j = 0; j < 16; ++j) { L += dred[j][0]; O += dred[j][1]; Cp += dred[j][2]; }
        blk[b * 4 + 0] = L;
        blk[b * 4 + 1] = O;
        blk[b * 4 + 2] = Cp;
        num_pos[b] = np;
    }

    int k = NEGPOS * np;
    if (k > PP - 1) k = PP - 1;
    if (k <= 0) {                    // uniform across block
        if (t == 0) blk[b * 4 + 3] = 0.0;
        return;
    }

    u32 prefix = 0, mask = 0, kk = (u32)k;

    for (int pass = 0; pass < 4; ++pass) {
        const int shift = 24 - 8 * pass;
        if (t < 256) hist[t] = 0;
        __syncthreads();
        #pragma unroll
        for (int r2 = 0; r2 < 25; ++r2) {
            const u32 uu = u[r2];
            const bool valid = (uu & mask) == prefix;
            const u32 bin = (uu >> shift) & 255u;
            u64 eq = __ballot(valid);
            #pragma unroll
            for (int bi = 0; bi < 8; ++bi) {
                const u64 bal = __ballot((bin >> bi) & 1u);
                eq &= ((bin >> bi) & 1u) ? bal : ~bal;
            }
            if (valid && ((int)__ffsll(eq) - 1 == lane))
                atomicAdd(&hist[bin], (u32)__popcll(eq));
        }
        __syncthreads();
        if (t < 256) {
            u32 above = 0;
            for (int bb = t + 1; bb < 256; ++bb) above += hist[bb];
            if (above < kk && above + hist[t] >= kk) {   // exactly one bin
                sh_prefix = prefix | ((u32)t << shift);
                sh_kk = kk - above;
            }
        }
        __syncthreads();
        prefix = sh_prefix;
        kk = sh_kk;
        mask |= (0xFFu << shift);
        __syncthreads();
    }

    const u32 thr_bits = prefix;
    const float thr = __uint_as_float(thr_bits);

    double ssum = 0.0;
    u32 cnt = 0;
    #pragma unroll
    for (int r2 = 0; r2 < 25; ++r2) {
        const u32 uu = u[r2];
        if (uu > thr_bits) { ssum += (double)__uint_as_float(uu); cnt++; }
    }
    #pragma unroll
    for (int d = 1; d < 64; d <<= 1) {
        ssum += __shfl_xor(ssum, d, 64);
        cnt  += __shfl_xor(cnt,  d, 64);
    }
    if (lane == 0) { dsum[w] = ssum; cred[w] = cnt; }
    __syncthreads();
    if (t == 0) {
        double S = 0.0; u32 cg = 0;
        #pragma unroll
        for (int j = 0; j < 16; ++j) { S += dsum[j]; cg += cred[j]; }
        S += (double)(k - (int)cg) * (double)thr;   // ties at threshold value
        blk[b * 4 + 3] = S;
    }
}

// ---------------- k_final ----------------
__global__ __launch_bounds__(64) void k_final(
    const double* __restrict__ blk,
    const int* __restrict__ num_pos,
    float* __restrict__ out)
{
    const int t = threadIdx.x;   // t == batch row
    double l  = blk[t * 4 + 0];
    double o  = blk[t * 4 + 1];
    double cp = blk[t * 4 + 2];
    double se = blk[t * 4 + 3];
    double n  = (double)num_pos[t];
    #pragma unroll
    for (int d = 1; d < 64; d <<= 1) {
        l  += __shfl_xor(l,  d, 64);
        o  += __shfl_xor(o,  d, 64);
        cp += __shfl_xor(cp, d, 64);
        se += __shfl_xor(se, d, 64);
        n  += __shfl_xor(n,  d, 64);
    }
    if (t == 0) {
        out[0] = (float)(l / n);
        out[1] = (float)((cp + se) / n);
        out[2] = (float)(o / n);
    }
}

extern "C" void kernel_launch(void* const* d_in, const int* in_sizes, int n_in,
                              void* d_out, int out_size, void* d_ws, size_t ws_size,
                              hipStream_t stream) {
    const float* loc_data  = (const float*)d_in[0];
    const float* conf_data = (const float*)d_in[1];
    const float* occ_data  = (const float*)d_in[2];
    const float* loc_t     = (const float*)d_in[3];
    const int*   conf_t    = (const int*)d_in[4];
    const float* occ_t     = (const float*)d_in[5];

    char* ws = (char*)d_ws;
    int*    numpos = (int*)ws;               // 64 ints
    double* blk    = (double*)(ws + 256);    // 64*4 doubles
    float*  mine   = (float*)(ws + 4096);    // ROWS floats

    k_main<<<NBLK, 256, 0, stream>>>(conf_data, conf_t, mine);
    k_select<<<BB, 1024, 0, stream>>>(mine, loc_data, loc_t,
                                      occ_data, occ_t, blk, numpos);
    k_final<<<1, 64, 0, stream>>>(blk, numpos, (float*)d_out);
}

// Round 15
// 156.927 us; speedup vs baseline: 1.2008x; 1.0495x over previous
//
#include <hip/hip_runtime.h>
#include <stdint.h>

#define BB 64
#define PP 24656
#define CC 81
#define NEGPOS 3
#define RPT 16                     // rows per wave tile
#define TFLT (RPT * CC)            // 1296 floats
#define NT ((BB * PP) / RPT)       // 98624 tiles
#define ROWS (BB * PP)
#define NPOSB 256                  // pos-worker blocks (dispatched first)
#define NMAIN 1792                 // main blocks: 7 blocks/CU
#define NBLK (NPOSB + NMAIN)

typedef unsigned int u32;
typedef unsigned long long u64;
typedef float f4v __attribute__((ext_vector_type(4)));
typedef int   i4v __attribute__((ext_vector_type(4)));

// ws layout:
//   [0]      int num_pos[64]           (k_select writes)
//   [256]    double blk[64][2]         (cp, sel) per batch row (k_select writes)
//   [1536]   double pp[NPOSB][2]       (a_l, a_o) per pos-block (k_fused writes)
//   [8192]   float mine[ROWS]          (sign bit = pos flag, magnitude = diff)

// ---------------- fused kernel: blocks [0,NPOSB) = pos loc/occ scan;
// blocks [NPOSB,NBLK) = NT-load lse/diff stream ----------------
__global__ __launch_bounds__(256, 7) void k_fused(
    const float* __restrict__ conf_data,
    const int*   __restrict__ conf_t,
    const float* __restrict__ loc_data,
    const float* __restrict__ loc_t,
    const float* __restrict__ occ_data,
    const float* __restrict__ occ_t,
    float* __restrict__ mine,
    double* __restrict__ pp)      // [NPOSB][2]
{
    __shared__ __align__(16) float tile[4][TFLT];   // 20736 B
    const int t = threadIdx.x;
    const int w = t >> 6;
    const int lane = t & 63;

    if (blockIdx.x < NPOSB) {
        // ---------- pos path: loc smooth-L1 + occlusion MSE ----------
        __shared__ double red[4][2];
        const int tid = blockIdx.x * 256 + t;
        const int nthr = NPOSB * 256;
        const int nchunk = ROWS / 4;
        double a_l = 0.0, a_o = 0.0;

        for (int c = tid; c < nchunk; c += nthr) {
            const i4v tc4 = __builtin_nontemporal_load(&((const i4v*)conf_t)[c]);
            #pragma unroll
            for (int e = 0; e < 4; ++e) {
                const int tc = tc4[e];
                if (tc > 0) {
                    const long i = (long)c * 4 + e;
                    const float4 ld4 = *(const float4*)(loc_data + i * 4);
                    const float4 lt4 = *(const float4*)(loc_t + i * 4);
                    float sl = 0.0f;
                    { float d = ld4.x - lt4.x, ad = fabsf(d); sl += (ad < 1.f) ? 0.5f*d*d : ad - 0.5f; }
                    { float d = ld4.y - lt4.y, ad = fabsf(d); sl += (ad < 1.f) ? 0.5f*d*d : ad - 0.5f; }
                    { float d = ld4.z - lt4.z, ad = fabsf(d); sl += (ad < 1.f) ? 0.5f*d*d : ad - 0.5f; }
                    { float d = ld4.w - lt4.w, ad = fabsf(d); sl += (ad < 1.f) ? 0.5f*d*d : ad - 0.5f; }
                    a_l += (double)sl;
                    const float ot = occ_t[i];
                    if (ot != -1.0f) { const float dd = occ_data[i] - ot; a_o += (double)(dd * dd); }
                }
            }
        }
        #pragma unroll
        for (int d = 1; d < 64; d <<= 1) {
            a_l += __shfl_xor(a_l, d, 64);
            a_o += __shfl_xor(a_o, d, 64);
        }
        if (lane == 0) { red[w][0] = a_l; red[w][1] = a_o; }
        __syncthreads();
        if (t == 0) {
            pp[blockIdx.x * 2 + 0] = red[0][0] + red[1][0] + red[2][0] + red[3][0];
            pp[blockIdx.x * 2 + 1] = red[0][1] + red[1][1] + red[2][1] + red[3][1];
        }
        return;
    }

    // ---------- main path: NT-load lse/diff stream ----------
    const int r = lane >> 2;        // row within tile
    const int s = lane & 3;         // quarter-row segment
    f4v* wt4 = (f4v*)tile[w];
    const float* wt = tile[w];
    const int wid = (blockIdx.x - NPOSB) * 4 + w;
    const int nw = NMAIN * 4;       // 7168 waves

    f4v b0, b1, b2, b3, b4, bt;
    int tc_nxt = 0;

    {
        const f4v* gb = (const f4v*)(conf_data + (long)wid * TFLT);
        b0 = __builtin_nontemporal_load(&gb[lane]);
        b1 = __builtin_nontemporal_load(&gb[64 + lane]);
        b2 = __builtin_nontemporal_load(&gb[128 + lane]);
        b3 = __builtin_nontemporal_load(&gb[192 + lane]);
        b4 = __builtin_nontemporal_load(&gb[256 + lane]);
        bt = b0;
        if (lane < 4)  bt = __builtin_nontemporal_load(&gb[320 + lane]);
        if (lane < 16) tc_nxt = __builtin_nontemporal_load(&conf_t[(long)wid * RPT + lane]);
    }

    for (int td = wid; td < NT; td += nw) {
        wt4[lane]       = b0;
        wt4[64 + lane]  = b1;
        wt4[128 + lane] = b2;
        wt4[192 + lane] = b3;
        wt4[256 + lane] = b4;
        if (lane < 4) wt4[320 + lane] = bt;
        const int tc_cur = tc_nxt;

        const int tdn = td + nw;
        if (tdn < NT) {
            const f4v* gb = (const f4v*)(conf_data + (long)tdn * TFLT);
            b0 = __builtin_nontemporal_load(&gb[lane]);
            b1 = __builtin_nontemporal_load(&gb[64 + lane]);
            b2 = __builtin_nontemporal_load(&gb[128 + lane]);
            b3 = __builtin_nontemporal_load(&gb[192 + lane]);
            b4 = __builtin_nontemporal_load(&gb[256 + lane]);
            if (lane < 4)  bt = __builtin_nontemporal_load(&gb[320 + lane]);
            if (lane < 16) tc_nxt = __builtin_nontemporal_load(&conf_t[(long)tdn * RPT + lane]);
        }

        const float* rp = wt + r * CC;
        const int start = (s == 0) ? 0 : (s * 20 + 1);     // 21|20|20|20 split
        float sum = (s == 0) ? __expf(rp[20]) : 0.0f;
        #pragma unroll
        for (int j = 0; j < 20; ++j) sum += __expf(rp[start + j]);
        sum += __shfl_xor(sum, 1, 64);
        sum += __shfl_xor(sum, 2, 64);

        const int tc_v = __shfl(tc_cur, r, 64);
        if (s == 0) {
            const float cat = rp[tc_v];
            const float diff = fmaxf(__logf(sum) - cat, 0.0f);
            mine[(long)td * RPT + r] = (tc_v > 0) ? -diff : diff;   // sign = pos flag
        }
    }
}

// ---------------- k_select: mine-only — np from sign bits, a_cp from
// magnitudes, radix k-th largest via ballot-match histogram. ----------------
__global__ __launch_bounds__(1024) void k_select(
    const float* __restrict__ mine,
    double* __restrict__ blk,     // [BB][2] (cp, sel)
    int* __restrict__ num_pos)    // [BB]
{
    __shared__ u32 hist[256];
    __shared__ u32 sh_prefix, sh_kk;
    __shared__ double dred[16];
    __shared__ int ired[16];
    __shared__ double dsum[16];
    __shared__ u32 cred[16];

    const int b = blockIdx.x;
    const int t = threadIdx.x;
    const int w = t >> 6;
    const int lane = t & 63;
    const float* row = mine + (long)b * PP;

    u32 u[25];
    int np_t = 0;
    double a_cp = 0.0;

    #pragma unroll
    for (int r2 = 0; r2 < 25; ++r2) {
        const int idx = t + (r2 << 10);
        u32 uu = 0u;
        if (idx < PP) {
            uu = __float_as_uint(row[idx]);
            if (uu >> 31) {                       // pos row
                ++np_t;
                a_cp += (double)__uint_as_float(uu & 0x7FFFFFFFu);
                uu = 0u;                          // exclude from mining
            }
        }
        u[r2] = uu;
    }

    #pragma unroll
    for (int d = 1; d < 64; d <<= 1) {
        a_cp += __shfl_xor(a_cp, d, 64);
        np_t += __shfl_xor(np_t, d, 64);
    }
    if (lane == 0) { dred[w] = a_cp; ired[w] = np_t; }
    __syncthreads();
    int np = 0;
    #pragma unroll
    for (int j = 0; j < 16; ++j) np += ired[j];
    if (t == 0) {
        double Cp = 0;
        #pragma unroll
        for (int j = 0; j < 16; ++j) Cp += dred[j];
        blk[b * 2 + 0] = Cp;
        num_pos[b] = np;
    }

    int k = NEGPOS * np;
    if (k > PP - 1) k = PP - 1;
    if (k <= 0) {
        if (t == 0) blk[b * 2 + 1] = 0.0;
        return;
    }

    u32 prefix = 0, mask = 0, kk = (u32)k;

    for (int pass = 0; pass < 4; ++pass) {
        const int shift = 24 - 8 * pass;
        if (t < 256) hist[t] = 0;
        __syncthreads();
        #pragma unroll
        for (int r2 = 0; r2 < 25; ++r2) {
            const u32 uu = u[r2];
            const bool valid = (uu & mask) == prefix;
            const u32 bin = (uu >> shift) & 255u;
            u64 eq = __ballot(valid);
            #pragma unroll
            for (int bi = 0; bi < 8; ++bi) {
                const u64 bal = __ballot((bin >> bi) & 1u);
                eq &= ((bin >> bi) & 1u) ? bal : ~bal;
            }
            if (valid && ((int)__ffsll(eq) - 1 == lane))
                atomicAdd(&hist[bin], (u32)__popcll(eq));
        }
        __syncthreads();
        if (t < 256) {
            u32 above = 0;
            for (int bb = t + 1; bb < 256; ++bb) above += hist[bb];
            if (above < kk && above + hist[t] >= kk) {
                sh_prefix = prefix | ((u32)t << shift);
                sh_kk = kk - above;
            }
        }
        __syncthreads();
        prefix = sh_prefix;
        kk = sh_kk;
        mask |= (0xFFu << shift);
        __syncthreads();
    }

    const u32 thr_bits = prefix;
    const float thr = __uint_as_float(thr_bits);

    double ssum = 0.0;
    u32 cnt = 0;
    #pragma unroll
    for (int r2 = 0; r2 < 25; ++r2) {
        const u32 uu = u[r2];
        if (uu > thr_bits) { ssum += (double)__uint_as_float(uu); cnt++; }
    }
    #pragma unroll
    for (int d = 1; d < 64; d <<= 1) {
        ssum += __shfl_xor(ssum, d, 64);
        cnt  += __shfl_xor(cnt,  d, 64);
    }
    if (lane == 0) { dsum[w] = ssum; cred[w] = cnt; }
    __syncthreads();
    if (t == 0) {
        double S = 0.0; u32 cg = 0;
        #pragma unroll
        for (int j = 0; j < 16; ++j) { S += dsum[j]; cg += cred[j]; }
        S += (double)(k - (int)cg) * (double)thr;
        blk[b * 2 + 1] = S;
    }
}

// ---------------- k_final: 64 threads reduce everything ----------------
__global__ __launch_bounds__(64) void k_final(
    const double* __restrict__ blk,      // [BB][2]
    const double* __restrict__ pp,       // [NPOSB][2]
    const int* __restrict__ num_pos,
    float* __restrict__ out)
{
    const int t = threadIdx.x;   // t == batch row index and pp stripe
    double cp = blk[t * 2 + 0];
    double se = blk[t * 2 + 1];
    double n  = (double)num_pos[t];
    double l = 0.0, o = 0.0;
    #pragma unroll
    for (int j = 0; j < NPOSB / 64; ++j) {      // 4 pp slots per thread
        l += pp[(t * (NPOSB / 64) + j) * 2 + 0];
        o += pp[(t * (NPOSB / 64) + j) * 2 + 1];
    }
    #pragma unroll
    for (int d = 1; d < 64; d <<= 1) {
        l  += __shfl_xor(l,  d, 64);
        o  += __shfl_xor(o,  d, 64);
        cp += __shfl_xor(cp, d, 64);
        se += __shfl_xor(se, d, 64);
        n  += __shfl_xor(n,  d, 64);
    }
    if (t == 0) {
        out[0] = (float)(l / n);
        out[1] = (float)((cp + se) / n);
        out[2] = (float)(o / n);
    }
}

extern "C" void kernel_launch(void* const* d_in, const int* in_sizes, int n_in,
                              void* d_out, int out_size, void* d_ws, size_t ws_size,
                              hipStream_t stream) {
    const float* loc_data  = (const float*)d_in[0];
    const float* conf_data = (const float*)d_in[1];
    const float* occ_data  = (const float*)d_in[2];
    const float* loc_t     = (const float*)d_in[3];
    const int*   conf_t    = (const int*)d_in[4];
    const float* occ_t     = (const float*)d_in[5];

    char* ws = (char*)d_ws;
    int*    numpos = (int*)ws;               // 64 ints
    double* blk    = (double*)(ws + 256);    // 64*2 doubles
    double* pp     = (double*)(ws + 1536);   // NPOSB*2 doubles
    float*  mine   = (float*)(ws + 8192);    // ROWS floats

    k_fused<<<NBLK, 256, 0, stream>>>(conf_data, conf_t, loc_data, loc_t,
                                      occ_data, occ_t, mine, pp);
    k_select<<<BB, 1024, 0, stream>>>(mine, blk, numpos);
    k_final<<<1, 64, 0, stream>>>(blk, pp, numpos, (float*)d_out);
}